// Round 15
// baseline (311.925 us; speedup 1.0000x reference)
//
#include <hip/hip_runtime.h>
#include <hip/hip_bf16.h>

#define DIMK 3
#define NPTS 30
#define KK   181
#define PP   24360
#define DEMB 190
#define VLD  192   // padded vec row stride (bf16 elements)
#define SNP  24576 // padded sort-row length = 16*1536

typedef __attribute__((ext_vector_type(8))) short bf16x8;
typedef __attribute__((ext_vector_type(4))) float f32x4;

__device__ __forceinline__ ushort f2bf(float f) {
    unsigned u = __float_as_uint(f);
    u += 0x7FFFu + ((u >> 16) & 1u);
    return (ushort)(u >> 16);
}

// ---------------------------------------------------------------------------
// Kernel 0: convert Ws_out (181x190 fp32) -> Abf (192x192 bf16, zero-padded)
// ---------------------------------------------------------------------------
__global__ __launch_bounds__(256) void k_prep(
    const float* __restrict__ W, ushort* __restrict__ Abf)
{
    int i = blockIdx.x * 256 + threadIdx.x;   // grid 144*256 = 36864 exact
    int k = i / 192, d = i - k * 192;
    Abf[i] = (k < KK && d < DEMB) ? f2bf(W[k * DEMB + d]) : (ushort)0;
}

// ---------------------------------------------------------------------------
// Kernel 1: per-permutation inner embed -> vec (PP x VLD, bf16)
// Round-15: TWO k's per lane with interleaved (ILP x2) pruned Batcher
// networks; tasks 73080 -> 36540. Group g=(p0,p1)=(2g,2g+1), 3 waves/group:
//   r=0: p0, kA=lane,     kB=lane+64   (shared G rows -> 12 b128/sort)
//   r=1: p0, kA=128+lane; p1, kB=128+lane (separate G rows)
//   r=2: p1, kA=lane,     kB=lane+64
// Pruned Batcher: INF pads at slots 30,31 never move (max->higher index),
// so all CEs with b>=30 are identities -> removed; v arrays are 30 floats.
// launch_bounds(256,4): VGPR cap 128 (live ~100) - no AGPR parking (r8 bug).
// Persistent: 1305 blocks = 5220 waves = 3*1740; 12180 groups / 1740 = 7.
// ---------------------------------------------------------------------------
#define NGRP 12180
#define GSTR 1740

__device__ __forceinline__ void decode_p(int p, int& c0, int& c1, int& c2) {
    int i0 = p / 812;            // 812 = 29*28
    int r  = p - i0 * 812;
    int i1 = r / 28;
    int i2 = r - i1 * 28;
    c0 = i0;
    c1 = i1 + (i1 >= c0 ? 1 : 0);
    int lo = min(c0, c1), hi = max(c0, c1);
    c2 = i2;
    if (c2 >= lo) c2++;
    if (c2 >= hi) c2++;
}

__global__ __launch_bounds__(256, 4) void k_inner(
    const float* __restrict__ M,      // 3 x 30
    const float* __restrict__ Ws_in,  // 181 x 3
    const float* __restrict__ Wd_in,  // 181 x 27
    ushort* __restrict__ vec)         // PP x VLD (bf16)
{
    __shared__ float Gs[NPTS * 32];
    __shared__ float WsS[192 * 3];
    __shared__ float WdS[192 * 28];

    const int tid = threadIdx.x;

    for (int i = tid; i < 192 * 3; i += 256) WsS[i] = (i < KK * 3) ? Ws_in[i] : 0.f;
    for (int i = tid; i < 192 * 28; i += 256) {
        int k = i / 28, m = i - k * 28;
        WdS[i] = (k < KK && m < 27) ? Wd_in[k * 27 + m] : 0.f;
    }
    for (int e = tid; e < NPTS * 32; e += 256) {
        int a = e >> 5, b = e & 31;
        Gs[e] = (b < NPTS)
            ? (M[a] * M[b] + M[NPTS + a] * M[NPTS + b] + M[2 * NPTS + a] * M[2 * NPTS + b])
            : 0.f;
    }
    __syncthreads();

    const int wave = tid >> 6;
    const int lane = tid & 63;
    const int wid = blockIdx.x * 4 + wave;    // 0..5219
    const int r   = wid % 3;
    const int gs  = wid / 3;                  // 0..1739

    const int kA = (r == 1) ? (128 + lane) : lane;
    const int kB = (r == 1) ? (128 + lane) : (64 + lane);

    const float INF = __builtin_inff();
    const float wA0 = WsS[kA * 3 + 0], wA1 = WsS[kA * 3 + 1], wA2 = WsS[kA * 3 + 2];
    const float wB0 = WsS[kB * 3 + 0], wB1 = WsS[kB * 3 + 1], wB2 = WsS[kB * 3 + 2];
    const float* wdA = WdS + kA * 28;
    const float* wdB = WdS + kB * 28;

    for (int g = gs; g < NGRP; g += GSTR) {
        const int pA = 2 * g + ((r == 2) ? 1 : 0);
        const int pB = 2 * g + ((r == 0) ? 0 : 1);

        int a0, a1, a2, b0, b1, b2;
        decode_p(pA, a0, a1, a2);
        decode_p(pB, b0, b1, b2);

        ushort* vrowA = vec + (long)pA * VLD;
        ushort* vrowB = vec + (long)pB * VLD;

        if (r != 1 && lane < 9) {   // gram entries, once per p (r=0->p0, r=2->p1)
            int i = lane / 3, j = lane % 3;
            int ci = (i == 0) ? a0 : ((i == 1) ? a1 : a2);
            int cj = (j == 0) ? a0 : ((j == 1) ? a1 : a2);
            vrowA[lane] = f2bf(Gs[(ci << 5) + cj]);
        }

        const unsigned xmA = (1u << a0) | (1u << a1) | (1u << a2);
        const unsigned xmB = (1u << b0) | (1u << b1) | (1u << b2);

        float vA[30], vB[30];

        if (r != 1) {
            // shared G rows
            const float* g0 = Gs + (a0 << 5);
            const float* g1 = Gs + (a1 << 5);
            const float* g2 = Gs + (a2 << 5);
#pragma unroll
            for (int q = 0; q < 8; ++q) {
                float4 x0 = *(const float4*)&g0[q * 4];
                float4 x1 = *(const float4*)&g1[q * 4];
                float4 x2 = *(const float4*)&g2[q * 4];
                int j0 = q * 4;
#define BUILD2(OFF, CX0, CX1, CX2)                                              \
                if (j0 + OFF < NPTS) {                                          \
                    bool ex = (xmA >> (j0 + OFF)) & 1u;                         \
                    vA[j0 + OFF] = ex ? INF : (wA0 * CX0 + wA1 * CX1 + wA2 * CX2); \
                    vB[j0 + OFF] = ex ? INF : (wB0 * CX0 + wB1 * CX1 + wB2 * CX2); \
                }
                BUILD2(0, x0.x, x1.x, x2.x)
                BUILD2(1, x0.y, x1.y, x2.y)
                BUILD2(2, x0.z, x1.z, x2.z)
                BUILD2(3, x0.w, x1.w, x2.w)
#undef BUILD2
            }
        } else {
            const float* gA0 = Gs + (a0 << 5);
            const float* gA1 = Gs + (a1 << 5);
            const float* gA2 = Gs + (a2 << 5);
            const float* gB0 = Gs + (b0 << 5);
            const float* gB1 = Gs + (b1 << 5);
            const float* gB2 = Gs + (b2 << 5);
#pragma unroll
            for (int q = 0; q < 8; ++q) {
                float4 x0 = *(const float4*)&gA0[q * 4];
                float4 x1 = *(const float4*)&gA1[q * 4];
                float4 x2 = *(const float4*)&gA2[q * 4];
                float4 y0 = *(const float4*)&gB0[q * 4];
                float4 y1 = *(const float4*)&gB1[q * 4];
                float4 y2 = *(const float4*)&gB2[q * 4];
                int j0 = q * 4;
#define BUILDAB(OFF, CX0, CX1, CX2, CY0, CY1, CY2)                              \
                if (j0 + OFF < NPTS) {                                          \
                    vA[j0 + OFF] = ((xmA >> (j0 + OFF)) & 1u) ? INF             \
                        : (wA0 * CX0 + wA1 * CX1 + wA2 * CX2);                  \
                    vB[j0 + OFF] = ((xmB >> (j0 + OFF)) & 1u) ? INF             \
                        : (wB0 * CY0 + wB1 * CY1 + wB2 * CY2);                  \
                }
                BUILDAB(0, x0.x, x1.x, x2.x, y0.x, y1.x, y2.x)
                BUILDAB(1, x0.y, x1.y, x2.y, y0.y, y1.y, y2.y)
                BUILDAB(2, x0.z, x1.z, x2.z, y0.z, y1.z, y2.z)
                BUILDAB(3, x0.w, x1.w, x2.w, y0.w, y1.w, y2.w)
#undef BUILDAB
            }
        }

        // Pruned Batcher odd-even mergesort (n=32 network, CEs with b>=30
        // removed: slots 30,31 would hold immovable INF pads), two
        // interleaved networks for ILP.
#pragma unroll
        for (int pw = 1; pw < 32; pw <<= 1) {
#pragma unroll
            for (int kk = pw; kk >= 1; kk >>= 1) {
#pragma unroll
                for (int j = kk % pw; j + kk < 32; j += 2 * kk) {
#pragma unroll
                    for (int i = 0; i < kk; ++i) {
                        int a = i + j, b = i + j + kk;
                        if (b < NPTS && (a / (pw * 2) == b / (pw * 2))) {
                            float x, y;
                            x = vA[a]; y = vA[b];
                            vA[a] = fminf(x, y); vA[b] = fmaxf(x, y);
                            x = vB[a]; y = vB[b];
                            vB[a] = fminf(x, y); vB[b] = fmaxf(x, y);
                        }
                    }
                }
            }
        }

        // dots (slot 27 always INF -> zero it; wd[27]=0 pad)
        vA[27] = 0.f;
        vB[27] = 0.f;
        float eA = 0.f, eB = 0.f;
#pragma unroll
        for (int q = 0; q < 7; ++q) {
            float4 w4a = *(const float4*)&wdA[q * 4];
            float4 w4b = *(const float4*)&wdB[q * 4];
            eA += w4a.x * vA[q * 4] + w4a.y * vA[q * 4 + 1]
                + w4a.z * vA[q * 4 + 2] + w4a.w * vA[q * 4 + 3];
            eB += w4b.x * vB[q * 4] + w4b.y * vB[q * 4 + 1]
                + w4b.z * vB[q * 4 + 2] + w4b.w * vB[q * 4 + 3];
        }

        if (kA < KK)       vrowA[9 + kA] = f2bf(eA);
        else if (kA < 183) vrowA[9 + kA] = 0;
        if (kB < KK)       vrowB[9 + kB] = f2bf(eB);
        else if (kB < 183) vrowB[9 + kB] = 0;
    }
}

// ---------------------------------------------------------------------------
// Kernel 2: sm2T[k][p] via bf16 MFMA [frozen, round 14]
// ---------------------------------------------------------------------------
__global__ __launch_bounds__(256) void k_gemm(
    const ushort* __restrict__ vecB,  // PP x 192 bf16
    const ushort* __restrict__ Abf,   // 192 x 192 bf16
    float* __restrict__ sm2T)         // 181 x PP fp32
{
    __shared__ ushort Asl[192 * 192];   // 73.7 KB

    const int tid = threadIdx.x;

    {
        const float4* s4 = (const float4*)Abf;
        float4* d4 = (float4*)Asl;
        for (int i = tid; i < 192 * 192 * 2 / 16; i += 256) d4[i] = s4[i];
    }

    const int wave = tid >> 6;
    const int lane = tid & 63;
    const int n = lane & 15;
    const int quad = lane >> 4;
    const int pBase = blockIdx.x * 64 + wave * 16;
    const int p = pBase + n;

    bf16x8 bfrag[6];
    if (p < PP) {
        const ushort* row = vecB + (long)p * VLD;
#pragma unroll
        for (int kc = 0; kc < 6; ++kc)
            bfrag[kc] = *(const bf16x8*)&row[kc * 32 + quad * 8];
    } else {
        bf16x8 z = {0, 0, 0, 0, 0, 0, 0, 0};
#pragma unroll
        for (int kc = 0; kc < 6; ++kc) bfrag[kc] = z;
    }
    __syncthreads();

#pragma unroll
    for (int kt = 0; kt < 12; ++kt) {
        f32x4 acc = {0.f, 0.f, 0.f, 0.f};
        const ushort* arow = Asl + (kt * 16 + n) * 192;
#pragma unroll
        for (int kc = 0; kc < 6; ++kc) {
            bf16x8 afrag = *(const bf16x8*)&arow[kc * 32 + quad * 8];
            acc = __builtin_amdgcn_mfma_f32_16x16x32_bf16(afrag, bfrag[kc], acc, 0, 0, 0);
        }
        if (p < PP) {
            int k0 = kt * 16 + quad * 4;
#pragma unroll
            for (int r = 0; r < 4; ++r) {
                int kg = k0 + r;
                if (kg < KK) sm2T[(long)kg * PP + p] = acc[r];
            }
        }
    }
}

// ---------------------------------------------------------------------------
// Kernel 3: per-k LSD radix sort, high 24 bits, 3 passes [frozen, round 12]
// ---------------------------------------------------------------------------
#define WAVES  16
#define WCHUNK 1536

__device__ __forceinline__ unsigned long long matchany9(unsigned d) {
    unsigned long long m = ~0ull;
#pragma unroll
    for (int b = 0; b < 9; ++b) {
        unsigned bit = (d >> b) & 1u;
        unsigned long long bal = __ballot(bit);
        m &= bit ? bal : ~bal;
    }
    return m;
}

__device__ __forceinline__ unsigned long long matchany8(unsigned d) {
    unsigned long long m = ~0ull;
#pragma unroll
    for (int b = 0; b < 8; ++b) {
        unsigned bit = (d >> b) & 1u;
        unsigned long long bal = __ballot(bit);
        m &= bit ? bal : ~bal;
    }
    return m;
}

__device__ __forceinline__ void scan_hist(unsigned* cntC, unsigned* cntZ,
                                          unsigned* tot, int tid) {
    if (tid < 256) {
        unsigned run = 0;
        for (int w = 0; w < WAVES; ++w) {
            unsigned t = cntC[w * 256 + tid];
            cntC[w * 256 + tid] = run;
            run += t;
        }
        tot[tid] = run;
    }
    __syncthreads();
    if (tid < 64) {
        unsigned t0 = tot[tid * 4], t1 = tot[tid * 4 + 1];
        unsigned t2 = tot[tid * 4 + 2], t3 = tot[tid * 4 + 3];
        unsigned s = t0 + t1 + t2 + t3;
        unsigned sc = s;
#pragma unroll
        for (int off = 1; off < 64; off <<= 1) {
            unsigned o = (unsigned)__shfl_up((int)sc, off, 64);
            if (tid >= off) sc += o;
        }
        unsigned ex = sc - s;
        tot[tid * 4]     = ex + t0;
        tot[tid * 4 + 1] = ex + t0 + t1;
        tot[tid * 4 + 2] = ex + t0 + t1 + t2;
        tot[tid * 4 + 3] = ex + s;
    } else if (cntZ) {
        for (int i = tid - 64; i < WAVES * 256; i += 1024 - 64) cntZ[i] = 0;
    }
    __syncthreads();
    for (int i = tid; i < WAVES * 256; i += 1024) {
        int d = i & 255;
        unsigned db = (d == 0) ? 0u : tot[d - 1];
        cntC[i] += db;
    }
    __syncthreads();
}

__global__ __launch_bounds__(1024) void k_sort(
    float* sm2T,
    unsigned* bufA,           // 181 x SNP scratch
    const float* __restrict__ WdOut,
    float* __restrict__ out)
{
    __shared__ unsigned keysL[SNP];
    __shared__ unsigned cntA[WAVES * 256];
    __shared__ unsigned cntB[WAVES * 256];
    __shared__ unsigned tot[256];
    __shared__ float red[WAVES];

    const int tid  = threadIdx.x;
    const int wave = tid >> 6;
    const int lane = tid & 63;
    const int k    = blockIdx.x;

    const unsigned* rowU = (const unsigned*)sm2T + (long)k * PP;
    unsigned* bA         = bufA + (long)k * SNP;
    const float* wrow    = WdOut + (long)k * PP;

    const int base_idx = wave * WCHUNK + lane;
    const int wbase = wave * 256;
    const unsigned long long lt_mask = (1ull << lane) - 1ull;

    for (int i = tid; i < WAVES * 256; i += 1024) cntA[i] = 0;
    for (int i = PP + tid; i < SNP; i += 1024) keysL[i] = 0xFFFFFFFFu;
    __syncthreads();

    for (int j = 0; j < 24; ++j) {
        int idx = base_idx + j * 64;
        if (idx < PP) {
            unsigned u = rowU[idx];
            u = (u & 0x80000000u) ? ~u : (u | 0x80000000u);
            atomicAdd(&cntA[wbase + ((u >> 8) & 255u)], 1u);
        }
    }
    __syncthreads();
    scan_hist(cntA, cntB, tot, tid);

    for (int j = 0; j < 24; ++j) {
        int idx = base_idx + j * 64;
        bool valid = (idx < PP);
        unsigned u = 0u;
        if (valid) {
            u = rowU[idx];
            u = (u & 0x80000000u) ? ~u : (u | 0x80000000u);
        }
        unsigned d9 = ((u >> 8) & 255u) | (valid ? 0u : 256u);
        unsigned long long mm = matchany9(d9);
        if (valid) {
            int leader = __ffsll(mm) - 1;
            unsigned myrank = (unsigned)__popcll(mm & lt_mask);
            unsigned old = 0;
            if (lane == leader)
                old = atomicAdd(&cntA[wbase + (d9 & 255u)], (unsigned)__popcll(mm));
            old = (unsigned)__shfl((int)old, leader, 64);
            unsigned dest = old + myrank;
            keysL[dest] = u;
            atomicAdd(&cntB[(dest / WCHUNK) * 256 + ((u >> 16) & 255u)], 1u);
        }
    }
    __syncthreads();
    if (tid == 0) cntB[15 * 256 + 255] += (SNP - PP);
    __syncthreads();
    scan_hist(cntB, cntA, tot, tid);

    for (int j = 0; j < 24; ++j) {
        int idx = base_idx + j * 64;
        unsigned u = keysL[idx];
        unsigned d = (u >> 16) & 255u;
        unsigned long long mm = matchany8(d);
        int leader = __ffsll(mm) - 1;
        unsigned myrank = (unsigned)__popcll(mm & lt_mask);
        unsigned old = 0;
        if (lane == leader)
            old = atomicAdd(&cntB[wbase + d], (unsigned)__popcll(mm));
        old = (unsigned)__shfl((int)old, leader, 64);
        unsigned dest = old + myrank;
        bA[dest] = u;
        atomicAdd(&cntA[(dest / WCHUNK) * 256 + ((u >> 24) & 255u)], 1u);
    }
    __syncthreads();
    scan_hist(cntA, (unsigned*)0, tot, tid);

    float local = 0.f;
    for (int j = 0; j < 24; ++j) {
        int idx = base_idx + j * 64;
        unsigned u = bA[idx];
        unsigned d = (u >> 24) & 255u;
        unsigned long long mm = matchany8(d);
        int leader = __ffsll(mm) - 1;
        unsigned myrank = (unsigned)__popcll(mm & lt_mask);
        unsigned old = 0;
        if (lane == leader)
            old = atomicAdd(&cntA[wbase + d], (unsigned)__popcll(mm));
        old = (unsigned)__shfl((int)old, leader, 64);
        unsigned dest = old + myrank;
        if (dest < PP) {
            unsigned raw = (u & 0x80000000u) ? (u & 0x7FFFFFFFu) : ~u;
            local += wrow[dest] * __uint_as_float(raw);
        }
    }

#pragma unroll
    for (int off = 32; off > 0; off >>= 1)
        local += __shfl_down(local, off, 64);
    if (lane == 0) red[wave] = local;
    __syncthreads();
    if (tid < WAVES) {
        float x = red[tid];
#pragma unroll
        for (int off = 8; off > 0; off >>= 1)
            x += __shfl_down(x, off, 64);
        if (tid == 0) out[k] = x;
    }
}

// ---------------------------------------------------------------------------
extern "C" void kernel_launch(void* const* d_in, const int* in_sizes, int n_in,
                              void* d_out, int out_size, void* d_ws, size_t ws_size,
                              hipStream_t stream) {
    const float* M      = (const float*)d_in[0];
    const float* Ws_in  = (const float*)d_in[1];
    const float* Wd_in  = (const float*)d_in[2];
    const float* Ws_out = (const float*)d_in[3];
    const float* Wd_out = (const float*)d_in[4];
    float* out = (float*)d_out;

    // workspace layout (35.5 MB):
    // [0, 17.79 MB):  bufA (181 x SNP u32); vecB (PP x 192 bf16) overlays head
    // [17.79, 35.43): sm2T (181 x PP fp32)
    // [35.43, +74KB): Abf (192 x 192 bf16)
    char* ws = (char*)d_ws;
    ushort*   vecB = (ushort*)ws;
    unsigned* bufA = (unsigned*)ws;
    float*    sm2T = (float*)(ws + (size_t)KK * SNP * 4);
    ushort*   Abf  = (ushort*)(ws + (size_t)KK * SNP * 4 + (size_t)KK * PP * 4);

    k_prep<<<144, 256, 0, stream>>>(Ws_out, Abf);

    k_inner<<<1305, 256, 0, stream>>>(M, Ws_in, Wd_in, vecB);

    k_gemm<<<(PP + 63) / 64, 256, 0, stream>>>(vecB, Abf, sm2T);

    k_sort<<<KK, 1024, 0, stream>>>(sm2T, bufA, Wd_out, out);
}

// Round 16
// 253.861 us; speedup vs baseline: 1.2287x; 1.2287x over previous
//
#include <hip/hip_runtime.h>
#include <hip/hip_bf16.h>

#define DIMK 3
#define NPTS 30
#define KK   181
#define PP   24360
#define DEMB 190
#define VLD  192   // padded vec row stride (bf16 elements)
#define SNP  24576 // padded sort-row length = 16*1536

typedef __attribute__((ext_vector_type(8))) short bf16x8;
typedef __attribute__((ext_vector_type(4))) float f32x4;

__device__ __forceinline__ ushort f2bf(float f) {
    unsigned u = __float_as_uint(f);
    u += 0x7FFFu + ((u >> 16) & 1u);
    return (ushort)(u >> 16);
}

// ---------------------------------------------------------------------------
// Kernel 0: convert Ws_out (181x190 fp32) -> Abf (192x192 bf16, zero-padded)
// ---------------------------------------------------------------------------
__global__ __launch_bounds__(256) void k_prep(
    const float* __restrict__ W, ushort* __restrict__ Abf)
{
    int i = blockIdx.x * 256 + threadIdx.x;   // grid 144*256 = 36864 exact
    int k = i / 192, d = i - k * 192;
    Abf[i] = (k < KK && d < DEMB) ? f2bf(W[k * DEMB + d]) : (ushort)0;
}

// ---------------------------------------------------------------------------
// Kernel 1: per-permutation inner embed -> vec (PP x VLD, bf16)
// [REVERTED verbatim to round-14: ONE sort array per lane. Rounds 8/15 both
// proved that 2-3 interleaved per-lane sort arrays get demoted to scratch
// (VGPR=64 + 150-300 MB of HBM spill traffic) regardless of launch bounds.]
// ---------------------------------------------------------------------------
__global__ __launch_bounds__(256, 5) void k_inner(
    const float* __restrict__ M,      // 3 x 30
    const float* __restrict__ Ws_in,  // 181 x 3
    const float* __restrict__ Wd_in,  // 181 x 27
    ushort* __restrict__ vec)         // PP x VLD (bf16)
{
    __shared__ float Gs[NPTS * 32];
    __shared__ float WsS[192 * 3];
    __shared__ float WdS[192 * 28];

    const int tid = threadIdx.x;

    for (int i = tid; i < 192 * 3; i += 256) WsS[i] = (i < KK * 3) ? Ws_in[i] : 0.f;
    for (int i = tid; i < 192 * 28; i += 256) {
        int k = i / 28, m = i - k * 28;
        WdS[i] = (k < KK && m < 27) ? Wd_in[k * 27 + m] : 0.f;
    }
    for (int e = tid; e < NPTS * 32; e += 256) {
        int a = e >> 5, b = e & 31;
        Gs[e] = (b < NPTS)
            ? (M[a] * M[b] + M[NPTS + a] * M[NPTS + b] + M[2 * NPTS + a] * M[2 * NPTS + b])
            : 0.f;
    }
    __syncthreads();

    const int wave = tid >> 6;
    const int lane = tid & 63;
    const int wid = blockIdx.x * 4 + wave;
    const int chunk = wid % 3;
    const int pstream = wid / 3;
    const int nstream = (chunk == 2) ? 1706 : 1707;
    const int k = chunk * 64 + lane;

    const float INF = __builtin_inff();
    const bool kvalid = (k < KK);
    const float w0 = WsS[k * 3 + 0];
    const float w1 = WsS[k * 3 + 1];
    const float w2 = WsS[k * 3 + 2];
    const float* wd = WdS + k * 28;

    for (int p = pstream; p < PP; p += nstream) {
        int i0 = p / 812;            // 812 = 29*28
        int r  = p - i0 * 812;
        int i1 = r / 28;
        int i2 = r - i1 * 28;
        int c0 = i0;
        int c1 = i1 + (i1 >= c0 ? 1 : 0);
        int lo = min(c0, c1), hi = max(c0, c1);
        int c2 = i2;
        if (c2 >= lo) c2++;
        if (c2 >= hi) c2++;

        ushort* vrow = vec + (long)p * VLD;

        if (chunk == 0 && lane < 9) {
            int i = lane / 3, j = lane % 3;
            int ci = (i == 0) ? c0 : ((i == 1) ? c1 : c2);
            int cj = (j == 0) ? c0 : ((j == 1) ? c1 : c2);
            vrow[lane] = f2bf(Gs[(ci << 5) + cj]);
        }

        const float* g0 = Gs + (c0 << 5);
        const float* g1 = Gs + (c1 << 5);
        const float* g2 = Gs + (c2 << 5);
        const unsigned xmask = (1u << c0) | (1u << c1) | (1u << c2);

        float v[32];
#pragma unroll
        for (int q = 0; q < 8; ++q) {
            float4 x0 = *(const float4*)&g0[q * 4];
            float4 x1 = *(const float4*)&g1[q * 4];
            float4 x2 = *(const float4*)&g2[q * 4];
            int j0 = q * 4;
            if (j0 + 0 < NPTS) { float val = w0 * x0.x + w1 * x1.x + w2 * x2.x;
                v[j0 + 0] = ((xmask >> (j0 + 0)) & 1u) ? INF : val; }
            if (j0 + 1 < NPTS) { float val = w0 * x0.y + w1 * x1.y + w2 * x2.y;
                v[j0 + 1] = ((xmask >> (j0 + 1)) & 1u) ? INF : val; }
            if (j0 + 2 < NPTS) { float val = w0 * x0.z + w1 * x1.z + w2 * x2.z;
                v[j0 + 2] = ((xmask >> (j0 + 2)) & 1u) ? INF : val; }
            if (j0 + 3 < NPTS) { float val = w0 * x0.w + w1 * x1.w + w2 * x2.w;
                v[j0 + 3] = ((xmask >> (j0 + 3)) & 1u) ? INF : val; }
        }
        v[30] = INF;
        v[31] = INF;

        // Batcher odd-even mergesort, n=32, ascending
#pragma unroll
        for (int pw = 1; pw < 32; pw <<= 1) {
#pragma unroll
            for (int kk = pw; kk >= 1; kk >>= 1) {
#pragma unroll
                for (int j = kk % pw; j + kk < 32; j += 2 * kk) {
#pragma unroll
                    for (int i = 0; i < kk; ++i) {
                        int a = i + j, b = i + j + kk;
                        if (a / (pw * 2) == b / (pw * 2)) {
                            float x = v[a], y = v[b];
                            v[a] = fminf(x, y);
                            v[b] = fmaxf(x, y);
                        }
                    }
                }
            }
        }

        if (kvalid) {
            v[27] = 0.f;
            float emb = 0.f;
#pragma unroll
            for (int q = 0; q < 7; ++q) {
                float4 w4 = *(const float4*)&wd[q * 4];
                emb += w4.x * v[q * 4] + w4.y * v[q * 4 + 1]
                     + w4.z * v[q * 4 + 2] + w4.w * v[q * 4 + 3];
            }
            vrow[9 + k] = f2bf(emb);
        } else if (k < 183) {
            vrow[9 + k] = 0;    // pad entries 190,191 stay zero
        }
    }
}

// ---------------------------------------------------------------------------
// Kernel 2: sm2T[k][p] via bf16 MFMA.
// Round-16: NO LDS staging. Total MFMA work is 0.75 us at peak; round-14's
// 73.7 KB LDS stage + barrier at 1.5 blocks/CU was the cost. A-fragments
// read straight from global (every block reads the same 74 KB -> L2-hot),
// kt-subtiles split across 2 blocks (bid&1) -> 2x waves (~12/CU), no
// barrier, VGPR ~40.
// ---------------------------------------------------------------------------
__global__ __launch_bounds__(256) void k_gemm(
    const ushort* __restrict__ vecB,  // PP x 192 bf16
    const ushort* __restrict__ Abf,   // 192 x 192 bf16
    float* __restrict__ sm2T)         // 181 x PP fp32
{
    const int tid  = threadIdx.x;
    const int bid  = blockIdx.x;
    const int tile = bid >> 1;        // p-tile (64 p's)
    const int half = bid & 1;         // kt half: 0 -> kt 0..5, 1 -> kt 6..11
    const int wave = tid >> 6;
    const int lane = tid & 63;
    const int n = lane & 15;
    const int quad = lane >> 4;
    const int p = tile * 64 + wave * 16 + n;

    bf16x8 bfrag[6];
    if (p < PP) {
        const ushort* row = vecB + (long)p * VLD;
#pragma unroll
        for (int kc = 0; kc < 6; ++kc)
            bfrag[kc] = *(const bf16x8*)&row[kc * 32 + quad * 8];
    } else {
        bf16x8 z = {0, 0, 0, 0, 0, 0, 0, 0};
#pragma unroll
        for (int kc = 0; kc < 6; ++kc) bfrag[kc] = z;
    }

#pragma unroll
    for (int i = 0; i < 6; ++i) {
        const int kt = half * 6 + i;
        f32x4 acc = {0.f, 0.f, 0.f, 0.f};
        const ushort* arow = Abf + (kt * 16 + n) * 192;
#pragma unroll
        for (int kc = 0; kc < 6; ++kc) {
            bf16x8 afrag = *(const bf16x8*)&arow[kc * 32 + quad * 8];
            acc = __builtin_amdgcn_mfma_f32_16x16x32_bf16(afrag, bfrag[kc], acc, 0, 0, 0);
        }
        if (p < PP) {
            int k0 = kt * 16 + quad * 4;
#pragma unroll
            for (int r = 0; r < 4; ++r) {
                int kg = k0 + r;
                if (kg < KK) sm2T[(long)kg * PP + p] = acc[r];
            }
        }
    }
}

// ---------------------------------------------------------------------------
// Kernel 3: per-k LSD radix sort, high 24 bits, 3 passes [frozen, round 12]
// ---------------------------------------------------------------------------
#define WAVES  16
#define WCHUNK 1536

__device__ __forceinline__ unsigned long long matchany9(unsigned d) {
    unsigned long long m = ~0ull;
#pragma unroll
    for (int b = 0; b < 9; ++b) {
        unsigned bit = (d >> b) & 1u;
        unsigned long long bal = __ballot(bit);
        m &= bit ? bal : ~bal;
    }
    return m;
}

__device__ __forceinline__ unsigned long long matchany8(unsigned d) {
    unsigned long long m = ~0ull;
#pragma unroll
    for (int b = 0; b < 8; ++b) {
        unsigned bit = (d >> b) & 1u;
        unsigned long long bal = __ballot(bit);
        m &= bit ? bal : ~bal;
    }
    return m;
}

__device__ __forceinline__ void scan_hist(unsigned* cntC, unsigned* cntZ,
                                          unsigned* tot, int tid) {
    if (tid < 256) {
        unsigned run = 0;
        for (int w = 0; w < WAVES; ++w) {
            unsigned t = cntC[w * 256 + tid];
            cntC[w * 256 + tid] = run;
            run += t;
        }
        tot[tid] = run;
    }
    __syncthreads();
    if (tid < 64) {
        unsigned t0 = tot[tid * 4], t1 = tot[tid * 4 + 1];
        unsigned t2 = tot[tid * 4 + 2], t3 = tot[tid * 4 + 3];
        unsigned s = t0 + t1 + t2 + t3;
        unsigned sc = s;
#pragma unroll
        for (int off = 1; off < 64; off <<= 1) {
            unsigned o = (unsigned)__shfl_up((int)sc, off, 64);
            if (tid >= off) sc += o;
        }
        unsigned ex = sc - s;
        tot[tid * 4]     = ex + t0;
        tot[tid * 4 + 1] = ex + t0 + t1;
        tot[tid * 4 + 2] = ex + t0 + t1 + t2;
        tot[tid * 4 + 3] = ex + s;
    } else if (cntZ) {
        for (int i = tid - 64; i < WAVES * 256; i += 1024 - 64) cntZ[i] = 0;
    }
    __syncthreads();
    for (int i = tid; i < WAVES * 256; i += 1024) {
        int d = i & 255;
        unsigned db = (d == 0) ? 0u : tot[d - 1];
        cntC[i] += db;
    }
    __syncthreads();
}

__global__ __launch_bounds__(1024) void k_sort(
    float* sm2T,
    unsigned* bufA,           // 181 x SNP scratch
    const float* __restrict__ WdOut,
    float* __restrict__ out)
{
    __shared__ unsigned keysL[SNP];
    __shared__ unsigned cntA[WAVES * 256];
    __shared__ unsigned cntB[WAVES * 256];
    __shared__ unsigned tot[256];
    __shared__ float red[WAVES];

    const int tid  = threadIdx.x;
    const int wave = tid >> 6;
    const int lane = tid & 63;
    const int k    = blockIdx.x;

    const unsigned* rowU = (const unsigned*)sm2T + (long)k * PP;
    unsigned* bA         = bufA + (long)k * SNP;
    const float* wrow    = WdOut + (long)k * PP;

    const int base_idx = wave * WCHUNK + lane;
    const int wbase = wave * 256;
    const unsigned long long lt_mask = (1ull << lane) - 1ull;

    for (int i = tid; i < WAVES * 256; i += 1024) cntA[i] = 0;
    for (int i = PP + tid; i < SNP; i += 1024) keysL[i] = 0xFFFFFFFFu;
    __syncthreads();

    for (int j = 0; j < 24; ++j) {
        int idx = base_idx + j * 64;
        if (idx < PP) {
            unsigned u = rowU[idx];
            u = (u & 0x80000000u) ? ~u : (u | 0x80000000u);
            atomicAdd(&cntA[wbase + ((u >> 8) & 255u)], 1u);
        }
    }
    __syncthreads();
    scan_hist(cntA, cntB, tot, tid);

    for (int j = 0; j < 24; ++j) {
        int idx = base_idx + j * 64;
        bool valid = (idx < PP);
        unsigned u = 0u;
        if (valid) {
            u = rowU[idx];
            u = (u & 0x80000000u) ? ~u : (u | 0x80000000u);
        }
        unsigned d9 = ((u >> 8) & 255u) | (valid ? 0u : 256u);
        unsigned long long mm = matchany9(d9);
        if (valid) {
            int leader = __ffsll(mm) - 1;
            unsigned myrank = (unsigned)__popcll(mm & lt_mask);
            unsigned old = 0;
            if (lane == leader)
                old = atomicAdd(&cntA[wbase + (d9 & 255u)], (unsigned)__popcll(mm));
            old = (unsigned)__shfl((int)old, leader, 64);
            unsigned dest = old + myrank;
            keysL[dest] = u;
            atomicAdd(&cntB[(dest / WCHUNK) * 256 + ((u >> 16) & 255u)], 1u);
        }
    }
    __syncthreads();
    if (tid == 0) cntB[15 * 256 + 255] += (SNP - PP);
    __syncthreads();
    scan_hist(cntB, cntA, tot, tid);

    for (int j = 0; j < 24; ++j) {
        int idx = base_idx + j * 64;
        unsigned u = keysL[idx];
        unsigned d = (u >> 16) & 255u;
        unsigned long long mm = matchany8(d);
        int leader = __ffsll(mm) - 1;
        unsigned myrank = (unsigned)__popcll(mm & lt_mask);
        unsigned old = 0;
        if (lane == leader)
            old = atomicAdd(&cntB[wbase + d], (unsigned)__popcll(mm));
        old = (unsigned)__shfl((int)old, leader, 64);
        unsigned dest = old + myrank;
        bA[dest] = u;
        atomicAdd(&cntA[(dest / WCHUNK) * 256 + ((u >> 24) & 255u)], 1u);
    }
    __syncthreads();
    scan_hist(cntA, (unsigned*)0, tot, tid);

    float local = 0.f;
    for (int j = 0; j < 24; ++j) {
        int idx = base_idx + j * 64;
        unsigned u = bA[idx];
        unsigned d = (u >> 24) & 255u;
        unsigned long long mm = matchany8(d);
        int leader = __ffsll(mm) - 1;
        unsigned myrank = (unsigned)__popcll(mm & lt_mask);
        unsigned old = 0;
        if (lane == leader)
            old = atomicAdd(&cntA[wbase + d], (unsigned)__popcll(mm));
        old = (unsigned)__shfl((int)old, leader, 64);
        unsigned dest = old + myrank;
        if (dest < PP) {
            unsigned raw = (u & 0x80000000u) ? (u & 0x7FFFFFFFu) : ~u;
            local += wrow[dest] * __uint_as_float(raw);
        }
    }

#pragma unroll
    for (int off = 32; off > 0; off >>= 1)
        local += __shfl_down(local, off, 64);
    if (lane == 0) red[wave] = local;
    __syncthreads();
    if (tid < WAVES) {
        float x = red[tid];
#pragma unroll
        for (int off = 8; off > 0; off >>= 1)
            x += __shfl_down(x, off, 64);
        if (tid == 0) out[k] = x;
    }
}

// ---------------------------------------------------------------------------
extern "C" void kernel_launch(void* const* d_in, const int* in_sizes, int n_in,
                              void* d_out, int out_size, void* d_ws, size_t ws_size,
                              hipStream_t stream) {
    const float* M      = (const float*)d_in[0];
    const float* Ws_in  = (const float*)d_in[1];
    const float* Wd_in  = (const float*)d_in[2];
    const float* Ws_out = (const float*)d_in[3];
    const float* Wd_out = (const float*)d_in[4];
    float* out = (float*)d_out;

    // workspace layout (35.5 MB):
    // [0, 17.79 MB):  bufA (181 x SNP u32); vecB (PP x 192 bf16) overlays head
    // [17.79, 35.43): sm2T (181 x PP fp32)
    // [35.43, +74KB): Abf (192 x 192 bf16)
    char* ws = (char*)d_ws;
    ushort*   vecB = (ushort*)ws;
    unsigned* bufA = (unsigned*)ws;
    float*    sm2T = (float*)(ws + (size_t)KK * SNP * 4);
    ushort*   Abf  = (ushort*)(ws + (size_t)KK * SNP * 4 + (size_t)KK * PP * 4);

    k_prep<<<144, 256, 0, stream>>>(Ws_out, Abf);

    k_inner<<<1280, 256, 0, stream>>>(M, Ws_in, Wd_in, vecB);

    k_gemm<<<((PP + 63) / 64) * 2, 256, 0, stream>>>(vecB, Abf, sm2T);

    k_sort<<<KK, 1024, 0, stream>>>(sm2T, bufA, Wd_out, out);
}